// Round 2
// baseline (3092.633 us; speedup 1.0000x reference)
//
#include <hip/hip_runtime.h>
#include <math.h>

// Problem constants
#define L_DIM 4096
#define B_DIM 4
#define H_DIM 512
#define E_DIM 1024
#define S_DIM 128
#define HALF  64
#define N_ROWS (B_DIM * L_DIM)      // 16384
#define NUV    (2 * E_DIM + S_DIM)  // 2176
#define MCH    1024                 // m-chunk size for kern materialization
#define LN_EPS 1e-5f
#define INV_SQRT_S 0.08838834764831845f  // 1/sqrt(128)

// GEMM tiling
#define TS 64
#define KS 16

// ---------------- workspace layout (floats) ----------------
// cos/sin tables, LN stats, u, v, braw, q, k, kern chunk, attnraw
// total = 48,791,552 floats = 186.1 MiB
#define OFF_COS  ((size_t)0)
#define OFF_SIN  (OFF_COS + (size_t)L_DIM * HALF)
#define OFF_MU   (OFF_SIN + (size_t)L_DIM * HALF)
#define OFF_RS   (OFF_MU + (size_t)N_ROWS)
#define OFF_U    (OFF_RS + (size_t)N_ROWS)
#define OFF_V    (OFF_U + (size_t)N_ROWS * E_DIM)
#define OFF_BR   (OFF_V + (size_t)N_ROWS * E_DIM)
#define OFF_Q    (OFF_BR + (size_t)N_ROWS * S_DIM)
#define OFF_K    (OFF_Q + (size_t)N_ROWS * S_DIM)
#define OFF_KC   (OFF_K + (size_t)N_ROWS * S_DIM)
#define OFF_AR   (OFF_KC + (size_t)L_DIM * MCH)

// ---------------- RoPE cos/sin tables ----------------
__global__ void k_tables(float* __restrict__ cosT, float* __restrict__ sinT) {
    int idx = blockIdx.x * 256 + threadIdx.x;
    if (idx >= L_DIM * HALF) return;
    int pos = idx >> 6;
    int j = idx & 63;
    float invf = (float)pow(10000.0, (double)j / 64.0);
    float angf = (float)pos * invf;
    double ang = (double)angf;
    cosT[idx] = (float)cos(ang);
    sinT[idx] = (float)sin(ang);
}

// ---------------- LayerNorm row stats (mu, rsqrt(var+eps)) ----------------
__global__ __launch_bounds__(256) void k_stats(const float* __restrict__ x,
                                               float* __restrict__ mu,
                                               float* __restrict__ rs) {
    int row = blockIdx.x;
    const float2* xr = (const float2*)(x + (size_t)row * H_DIM);
    float2 v = xr[threadIdx.x];
    float s = v.x + v.y;
    float s2 = v.x * v.x + v.y * v.y;
#pragma unroll
    for (int off = 32; off > 0; off >>= 1) {
        s  += __shfl_down(s, off);
        s2 += __shfl_down(s2, off);
    }
    __shared__ float red[8];
    int wid = threadIdx.x >> 6, lane = threadIdx.x & 63;
    if (lane == 0) { red[wid] = s; red[4 + wid] = s2; }
    __syncthreads();
    if (threadIdx.x == 0) {
        float ts = red[0] + red[1] + red[2] + red[3];
        float ts2 = red[4] + red[5] + red[6] + red[7];
        float m = ts / (float)H_DIM;
        float var = ts2 / (float)H_DIM - m * m;
        mu[row] = m;
        rs[row] = rsqrtf(var + LN_EPS);
    }
}

// ---------------- GEMM 1: uv = silu(LN(x) @ uv_w^T + uv_b) ----------------
// LN applied on the fly while staging A. Scatter outputs to u / v / braw.
__global__ __launch_bounds__(256) void k_gemm_uv(const float* __restrict__ x,
                                                 const float* __restrict__ mu,
                                                 const float* __restrict__ rs,
                                                 const float* __restrict__ lnw,
                                                 const float* __restrict__ lnb,
                                                 const float* __restrict__ w,
                                                 const float* __restrict__ bias,
                                                 float* __restrict__ u,
                                                 float* __restrict__ v,
                                                 float* __restrict__ braw) {
    __shared__ float As[KS][TS + 4];
    __shared__ float Bs[KS][TS + 4];
    const int brow = blockIdx.y * TS, bcol = blockIdx.x * TS;
    const int tid = threadIdx.x;
    const int lrow = tid >> 2, lcol = (tid & 3) << 2;
    const int tx = tid & 15, ty = tid >> 4;
    float acc[4][4] = {};
    const float m_ = mu[brow + lrow];
    const float r_ = rs[brow + lrow];
    for (int k0 = 0; k0 < H_DIM; k0 += KS) {
        float4 a4 = *(const float4*)(x + (size_t)(brow + lrow) * H_DIM + k0 + lcol);
        float4 w4 = *(const float4*)(lnw + k0 + lcol);
        float4 c4 = *(const float4*)(lnb + k0 + lcol);
        a4.x = (a4.x - m_) * r_ * w4.x + c4.x;
        a4.y = (a4.y - m_) * r_ * w4.y + c4.y;
        a4.z = (a4.z - m_) * r_ * w4.z + c4.z;
        a4.w = (a4.w - m_) * r_ * w4.w + c4.w;
        float4 b4 = *(const float4*)(w + (size_t)(bcol + lrow) * H_DIM + k0 + lcol);
        As[lcol + 0][lrow] = a4.x; As[lcol + 1][lrow] = a4.y;
        As[lcol + 2][lrow] = a4.z; As[lcol + 3][lrow] = a4.w;
        Bs[lcol + 0][lrow] = b4.x; Bs[lcol + 1][lrow] = b4.y;
        Bs[lcol + 2][lrow] = b4.z; Bs[lcol + 3][lrow] = b4.w;
        __syncthreads();
#pragma unroll
        for (int kk = 0; kk < KS; ++kk) {
            float4 av = *(const float4*)&As[kk][ty << 2];
            float4 bv = *(const float4*)&Bs[kk][tx << 2];
            const float a[4] = {av.x, av.y, av.z, av.w};
            const float b[4] = {bv.x, bv.y, bv.z, bv.w};
#pragma unroll
            for (int i = 0; i < 4; ++i)
#pragma unroll
                for (int j = 0; j < 4; ++j)
                    acc[i][j] = fmaf(a[i], b[j], acc[i][j]);
        }
        __syncthreads();
    }
    // epilogue: bias + silu, scatter
#pragma unroll
    for (int i = 0; i < 4; ++i) {
        int m = brow + (ty << 2) + i;
        int n0 = bcol + (tx << 2);
        float4 o;
        float* op = &o.x;
#pragma unroll
        for (int j = 0; j < 4; ++j) {
            float t = acc[i][j] + bias[n0 + j];
            op[j] = t / (1.f + expf(-t));
        }
        if (n0 < E_DIM)
            *(float4*)(u + (size_t)m * E_DIM + n0) = o;
        else if (n0 < 2 * E_DIM)
            *(float4*)(v + (size_t)m * E_DIM + (n0 - E_DIM)) = o;
        else
            *(float4*)(braw + (size_t)m * S_DIM + (n0 - 2 * E_DIM)) = o;
    }
}

// ---------------- gamma/beta + RoPE -> q, k ----------------
__global__ __launch_bounds__(256) void k_prep(const float* __restrict__ braw,
                                              const float* __restrict__ gamma,
                                              const float* __restrict__ beta,
                                              const float* __restrict__ cosT,
                                              const float* __restrict__ sinT,
                                              float* __restrict__ q,
                                              float* __restrict__ kq) {
    int idx = blockIdx.x * 256 + threadIdx.x;  // N_ROWS * 64 threads
    int row = idx >> 6;
    int j = idx & 63;
    int l = row & (L_DIM - 1);
    float b1 = braw[(size_t)row * S_DIM + j];
    float b2 = braw[(size_t)row * S_DIM + j + HALF];
    float c = cosT[l * HALF + j];
    float s = sinT[l * HALF + j];
    {
        float x1 = b1 * gamma[j] + beta[j];
        float x2 = b2 * gamma[j + HALF] + beta[j + HALF];
        q[(size_t)row * S_DIM + j] = x1 * c - x2 * s;
        q[(size_t)row * S_DIM + j + HALF] = x2 * c + x1 * s;
    }
    {
        float x1 = b1 * gamma[S_DIM + j] + beta[S_DIM + j];
        float x2 = b2 * gamma[S_DIM + j + HALF] + beta[S_DIM + j + HALF];
        kq[(size_t)row * S_DIM + j] = x1 * c - x2 * s;
        kq[(size_t)row * S_DIM + j + HALF] = x2 * c + x1 * s;
    }
}

// ---------------- GEMM 2: kern_chunk = relu(q @ k_chunk^T / sqrt(S))^2 -----
// q: [L][S], kc: [MCH][S] (chunk of k), kern: [L][MCH]
__global__ __launch_bounds__(256) void k_gemm_qk(const float* __restrict__ q,
                                                 const float* __restrict__ kc,
                                                 float* __restrict__ kern) {
    __shared__ float As[KS][TS + 4];
    __shared__ float Bs[KS][TS + 4];
    const int brow = blockIdx.y * TS, bcol = blockIdx.x * TS;
    const int tid = threadIdx.x;
    const int lrow = tid >> 2, lcol = (tid & 3) << 2;
    const int tx = tid & 15, ty = tid >> 4;
    float acc[4][4] = {};
    for (int k0 = 0; k0 < S_DIM; k0 += KS) {
        float4 a4 = *(const float4*)(q + (size_t)(brow + lrow) * S_DIM + k0 + lcol);
        float4 b4 = *(const float4*)(kc + (size_t)(bcol + lrow) * S_DIM + k0 + lcol);
        As[lcol + 0][lrow] = a4.x; As[lcol + 1][lrow] = a4.y;
        As[lcol + 2][lrow] = a4.z; As[lcol + 3][lrow] = a4.w;
        Bs[lcol + 0][lrow] = b4.x; Bs[lcol + 1][lrow] = b4.y;
        Bs[lcol + 2][lrow] = b4.z; Bs[lcol + 3][lrow] = b4.w;
        __syncthreads();
#pragma unroll
        for (int kk = 0; kk < KS; ++kk) {
            float4 av = *(const float4*)&As[kk][ty << 2];
            float4 bv = *(const float4*)&Bs[kk][tx << 2];
            const float a[4] = {av.x, av.y, av.z, av.w};
            const float b[4] = {bv.x, bv.y, bv.z, bv.w};
#pragma unroll
            for (int i = 0; i < 4; ++i)
#pragma unroll
                for (int j = 0; j < 4; ++j)
                    acc[i][j] = fmaf(a[i], b[j], acc[i][j]);
        }
        __syncthreads();
    }
#pragma unroll
    for (int i = 0; i < 4; ++i) {
        int m = brow + (ty << 2) + i;
        int n0 = bcol + (tx << 2);
        float4 o;
        float* op = &o.x;
#pragma unroll
        for (int j = 0; j < 4; ++j) {
            float t = fmaxf(acc[i][j] * INV_SQRT_S, 0.f);
            op[j] = t * t;
        }
        *(float4*)(kern + (size_t)m * MCH + n0) = o;
    }
}

// ---------------- GEMM 3: attnraw (+)= kern_chunk @ v_chunk ----------------
// kern: [L][MCH], vc: [MCH][E], ar: [L][E]
__global__ __launch_bounds__(256) void k_gemm_av(const float* __restrict__ kern,
                                                 const float* __restrict__ vc,
                                                 float* __restrict__ ar,
                                                 int first) {
    __shared__ float As[KS][TS + 4];
    __shared__ float Bs[KS][TS + 4];
    const int brow = blockIdx.y * TS, bcol = blockIdx.x * TS;
    const int tid = threadIdx.x;
    const int lrow = tid >> 2, lcol = (tid & 3) << 2;
    const int brl = tid >> 4, bcl = (tid & 15) << 2;
    const int tx = tid & 15, ty = tid >> 4;
    float acc[4][4] = {};
    for (int k0 = 0; k0 < MCH; k0 += KS) {
        float4 a4 = *(const float4*)(kern + (size_t)(brow + lrow) * MCH + k0 + lcol);
        float4 b4 = *(const float4*)(vc + (size_t)(k0 + brl) * E_DIM + bcol + bcl);
        As[lcol + 0][lrow] = a4.x; As[lcol + 1][lrow] = a4.y;
        As[lcol + 2][lrow] = a4.z; As[lcol + 3][lrow] = a4.w;
        *(float4*)&Bs[brl][bcl] = b4;
        __syncthreads();
#pragma unroll
        for (int kk = 0; kk < KS; ++kk) {
            float4 av = *(const float4*)&As[kk][ty << 2];
            float4 bv = *(const float4*)&Bs[kk][tx << 2];
            const float a[4] = {av.x, av.y, av.z, av.w};
            const float b[4] = {bv.x, bv.y, bv.z, bv.w};
#pragma unroll
            for (int i = 0; i < 4; ++i)
#pragma unroll
                for (int j = 0; j < 4; ++j)
                    acc[i][j] = fmaf(a[i], b[j], acc[i][j]);
        }
        __syncthreads();
    }
#pragma unroll
    for (int i = 0; i < 4; ++i) {
        int m = brow + (ty << 2) + i;
        int n0 = bcol + (tx << 2);
        float4 o;
        o.x = acc[i][0]; o.y = acc[i][1]; o.z = acc[i][2]; o.w = acc[i][3];
        float4* dst = (float4*)(ar + (size_t)m * E_DIM + n0);
        if (!first) {
            float4 old = *dst;
            o.x += old.x; o.y += old.y; o.z += old.z; o.w += old.w;
        }
        *dst = o;
    }
}

// ---------------- GEMM 4: out = (u ⊙ attnraw) @ o_w^T + o_b + x ------------
// ar: [L][E], ub: [L][E], ow: [H][E]
__global__ __launch_bounds__(256) void k_gemm_out(const float* __restrict__ ar,
                                                  const float* __restrict__ ub,
                                                  const float* __restrict__ ow,
                                                  const float* __restrict__ ob,
                                                  const float* __restrict__ xb,
                                                  float* __restrict__ outb) {
    __shared__ float As[KS][TS + 4];
    __shared__ float Bs[KS][TS + 4];
    const int brow = blockIdx.y * TS, bcol = blockIdx.x * TS;
    const int tid = threadIdx.x;
    const int lrow = tid >> 2, lcol = (tid & 3) << 2;
    const int tx = tid & 15, ty = tid >> 4;
    float acc[4][4] = {};
    for (int k0 = 0; k0 < E_DIM; k0 += KS) {
        float4 a4 = *(const float4*)(ar + (size_t)(brow + lrow) * E_DIM + k0 + lcol);
        float4 u4 = *(const float4*)(ub + (size_t)(brow + lrow) * E_DIM + k0 + lcol);
        a4.x *= u4.x; a4.y *= u4.y; a4.z *= u4.z; a4.w *= u4.w;
        float4 b4 = *(const float4*)(ow + (size_t)(bcol + lrow) * E_DIM + k0 + lcol);
        As[lcol + 0][lrow] = a4.x; As[lcol + 1][lrow] = a4.y;
        As[lcol + 2][lrow] = a4.z; As[lcol + 3][lrow] = a4.w;
        Bs[lcol + 0][lrow] = b4.x; Bs[lcol + 1][lrow] = b4.y;
        Bs[lcol + 2][lrow] = b4.z; Bs[lcol + 3][lrow] = b4.w;
        __syncthreads();
#pragma unroll
        for (int kk = 0; kk < KS; ++kk) {
            float4 av = *(const float4*)&As[kk][ty << 2];
            float4 bv = *(const float4*)&Bs[kk][tx << 2];
            const float a[4] = {av.x, av.y, av.z, av.w};
            const float b[4] = {bv.x, bv.y, bv.z, bv.w};
#pragma unroll
            for (int i = 0; i < 4; ++i)
#pragma unroll
                for (int j = 0; j < 4; ++j)
                    acc[i][j] = fmaf(a[i], b[j], acc[i][j]);
        }
        __syncthreads();
    }
#pragma unroll
    for (int i = 0; i < 4; ++i) {
        int m = brow + (ty << 2) + i;
        int n0 = bcol + (tx << 2);
        float4 xv = *(const float4*)(xb + (size_t)m * H_DIM + n0);
        float4 o;
        o.x = acc[i][0] + ob[n0 + 0] + xv.x;
        o.y = acc[i][1] + ob[n0 + 1] + xv.y;
        o.z = acc[i][2] + ob[n0 + 2] + xv.z;
        o.w = acc[i][3] + ob[n0 + 3] + xv.w;
        *(float4*)(outb + (size_t)m * H_DIM + n0) = o;
    }
}

extern "C" void kernel_launch(void* const* d_in, const int* in_sizes, int n_in,
                              void* d_out, int out_size, void* d_ws, size_t ws_size,
                              hipStream_t stream) {
    const float* x     = (const float*)d_in[0];
    const float* ln_w  = (const float*)d_in[1];
    const float* ln_b  = (const float*)d_in[2];
    const float* uv_w  = (const float*)d_in[3];
    const float* uv_b  = (const float*)d_in[4];
    const float* gamma = (const float*)d_in[5];
    const float* beta  = (const float*)d_in[6];
    const float* o_w   = (const float*)d_in[7];
    const float* o_b   = (const float*)d_in[8];
    float* out = (float*)d_out;
    float* ws = (float*)d_ws;

    float* cosT = ws + OFF_COS;
    float* sinT = ws + OFF_SIN;
    float* muA  = ws + OFF_MU;
    float* rsA  = ws + OFF_RS;
    float* u    = ws + OFF_U;
    float* v    = ws + OFF_V;
    float* braw = ws + OFF_BR;
    float* q    = ws + OFF_Q;
    float* kq   = ws + OFF_K;
    float* kern = ws + OFF_KC;
    float* ar   = ws + OFF_AR;

    k_tables<<<(L_DIM * HALF + 255) / 256, 256, 0, stream>>>(cosT, sinT);
    k_stats<<<N_ROWS, 256, 0, stream>>>(x, muA, rsA);
    k_gemm_uv<<<dim3(NUV / TS, N_ROWS / TS), 256, 0, stream>>>(
        x, muA, rsA, ln_w, ln_b, uv_w, uv_b, u, v, braw);
    k_prep<<<(N_ROWS * HALF) / 256, 256, 0, stream>>>(braw, gamma, beta, cosT, sinT, q, kq);

    for (int b = 0; b < B_DIM; ++b) {
        const float* qb = q + (size_t)b * L_DIM * S_DIM;
        const float* ub = u + (size_t)b * L_DIM * E_DIM;
        const float* xb = x + (size_t)b * L_DIM * H_DIM;
        float* outb = out + (size_t)b * L_DIM * H_DIM;
        for (int c = 0; c < L_DIM / MCH; ++c) {
            const float* kc = kq + ((size_t)b * L_DIM + (size_t)c * MCH) * S_DIM;
            const float* vc = v + ((size_t)b * L_DIM + (size_t)c * MCH) * E_DIM;
            k_gemm_qk<<<dim3(MCH / TS, L_DIM / TS), 256, 0, stream>>>(qb, kc, kern);
            k_gemm_av<<<dim3(E_DIM / TS, L_DIM / TS), 256, 0, stream>>>(kern, vc, ar, c == 0);
        }
        k_gemm_out<<<dim3(H_DIM / TS, L_DIM / TS), 256, 0, stream>>>(ar, ub, o_w, o_b, xb, outb);
    }
}

// Round 3
// 435.631 us; speedup vs baseline: 7.0992x; 7.0992x over previous
//
#include <hip/hip_runtime.h>
#include <math.h>

// Problem constants
#define L_DIM 4096
#define B_DIM 4
#define H_DIM 512
#define E_DIM 1024
#define S_DIM 128
#define HALF  64
#define N_ROWS 16384
#define NUV   2176
#define LN_EPS 1e-5f
#define INV_SQRT_S 0.08838834764831845f

typedef _Float16 f16;
typedef __attribute__((ext_vector_type(8))) _Float16 half8;
typedef __attribute__((ext_vector_type(4))) _Float16 half4;
typedef __attribute__((ext_vector_type(4))) float f32x4;

// ---------------- workspace byte offsets (all 256B aligned) ----------------
#define OFF_COS  ((size_t)0)                       // f32 [4096][64]   1 MB
#define OFF_SIN  (OFF_COS + 1048576)               // f32 [4096][64]   1 MB
#define OFF_MU   (OFF_SIN + 1048576)               // f32 [16384]
#define OFF_RS   (OFF_MU + 65536)                  // f32 [16384]
#define OFF_XN   (OFF_RS + 65536)                  // f16 [16384][512] 16 MB
#define OFF_WUV  (OFF_XN + 16777216)               // f16 [2176][512]  2.2 MB
#define OFF_WO   (OFF_WUV + 2228224)               // f16 [512][1024]  1 MB
#define OFF_U    (OFF_WO + 1048576)                // f16 [16384][1024] 32 MB
#define OFF_VT   (OFF_U + 33554432)                // f16 [4][1024][4096] 32 MB
#define OFF_BR   (OFF_VT + 33554432)               // f32 [16384][128] 8 MB
#define OFF_Q    (OFF_BR + 8388608)                // f16 [16384][128] 4 MB
#define OFF_K    (OFF_Q + 4194304)                 // f16 [16384][128] 4 MB
#define OFF_KC   (OFF_K + 4194304)                 // f16 [4][1024][4096] 32 MB
#define OFF_AUB  (OFF_KC + 33554432)               // f16 [16384][1024] 32 MB
// end = 173,277,184 B = 165.3 MiB  (r1's 186.1 MiB fit, so this fits)

// ---------------- RoPE cos/sin tables ----------------
__global__ void k_tables(float* __restrict__ cosT, float* __restrict__ sinT) {
    int idx = blockIdx.x * 256 + threadIdx.x;
    if (idx >= L_DIM * HALF) return;
    int pos = idx >> 6;
    int j = idx & 63;
    float invf = (float)pow(10000.0, (double)j / 64.0);
    float angf = (float)pos * invf;
    double ang = (double)angf;
    cosT[idx] = (float)cos(ang);
    sinT[idx] = (float)sin(ang);
}

// ---------------- LayerNorm row stats ----------------
__global__ __launch_bounds__(256) void k_stats(const float* __restrict__ x,
                                               float* __restrict__ mu,
                                               float* __restrict__ rs) {
    int row = blockIdx.x;
    const float2* xr = (const float2*)(x + (size_t)row * H_DIM);
    float2 v = xr[threadIdx.x];
    float s = v.x + v.y;
    float s2 = v.x * v.x + v.y * v.y;
#pragma unroll
    for (int off = 32; off > 0; off >>= 1) {
        s  += __shfl_down(s, off);
        s2 += __shfl_down(s2, off);
    }
    __shared__ float red[8];
    int wid = threadIdx.x >> 6, lane = threadIdx.x & 63;
    if (lane == 0) { red[wid] = s; red[4 + wid] = s2; }
    __syncthreads();
    if (threadIdx.x == 0) {
        float ts = red[0] + red[1] + red[2] + red[3];
        float ts2 = red[4] + red[5] + red[6] + red[7];
        float m = ts / (float)H_DIM;
        float var = ts2 / (float)H_DIM - m * m;
        mu[row] = m;
        rs[row] = rsqrtf(var + LN_EPS);
    }
}

// ---------------- LN apply + f16 convert ----------------
__global__ __launch_bounds__(256) void k_xn(const float* __restrict__ x,
                                            const float* __restrict__ mu,
                                            const float* __restrict__ rs,
                                            const float* __restrict__ lnw,
                                            const float* __restrict__ lnb,
                                            f16* __restrict__ xn) {
    int gid = blockIdx.x * 256 + threadIdx.x;  // N_ROWS*128 total
    int row = gid >> 7;
    int c = (gid & 127) << 2;
    float m = mu[row], r = rs[row];
    float4 xv = *(const float4*)(x + (size_t)row * H_DIM + c);
    float4 wv = *(const float4*)(lnw + c);
    float4 bv = *(const float4*)(lnb + c);
    half4 o;
    o[0] = (f16)((xv.x - m) * r * wv.x + bv.x);
    o[1] = (f16)((xv.y - m) * r * wv.y + bv.y);
    o[2] = (f16)((xv.z - m) * r * wv.z + bv.z);
    o[3] = (f16)((xv.w - m) * r * wv.w + bv.w);
    *(half4*)(xn + (size_t)row * H_DIM + c) = o;
}

// ---------------- weight conversion (uv_w then o_w) ----------------
__global__ __launch_bounds__(256) void k_cvt_w(const float* __restrict__ uvw,
                                               const float* __restrict__ ow,
                                               f16* __restrict__ duv,
                                               f16* __restrict__ dow) {
    int gid = blockIdx.x * 256 + threadIdx.x;  // 409600 total
    int i4 = gid << 2;
    const float* src;
    f16* dst;
    int off;
    if (i4 < NUV * H_DIM) { src = uvw; dst = duv; off = i4; }
    else { src = ow; dst = dow; off = i4 - NUV * H_DIM; }
    float4 v = *(const float4*)(src + off);
    half4 o = {(f16)v.x, (f16)v.y, (f16)v.z, (f16)v.w};
    *(half4*)(dst + off) = o;
}

// ---------------- MFMA core: C = A · B^T, A[M][K] f16 K-major, B[N][K] f16 ----
// 4 waves (2x2), wave tile (MT*16)x(NT*16), BK=64, XOR-swizzled LDS +
// global_load_lds width-16 staging (pre-swizzled global source, m173 pattern).
__device__ __forceinline__ void gload16(const void* g, void* l) {
    __builtin_amdgcn_global_load_lds(
        (const __attribute__((address_space(1))) unsigned int*)g,
        (__attribute__((address_space(3))) unsigned int*)l, 16, 0, 0);
}

template <int MT, int NT>
__device__ __forceinline__ void mfma_core(const char* Ab, int lda_b,
                                          const char* Bb, int ldb_b,
                                          int K, f16* lds, f32x4 acc[MT][NT]) {
    constexpr int BM = 32 * MT, BN = 32 * NT;
    constexpr int ISS = (BM + BN) / 32;  // global_load_lds issues per wave
    const int tid = threadIdx.x;
    const int lane = tid & 63;
    const int wv = tid >> 6;
    const int wr = wv >> 1, wc = wv & 1;
    char* ldsc = (char*)lds;
    for (int k0 = 0; k0 < K; k0 += 64) {
#pragma unroll
        for (int i = 0; i < ISS; ++i) {
            const int ellb = (wv * ISS + i) << 10;   // uniform LDS byte base
            const int ell = ellb + (lane << 4);      // lane's linear byte slot
            int row, kb;
            const char* bas;
            int ld;
            if (ell < BM * 128) { row = ell >> 7; kb = ell & 127; bas = Ab; ld = lda_b; }
            else { const int e2 = ell - BM * 128; row = e2 >> 7; kb = e2 & 127; bas = Bb; ld = ldb_b; }
            kb ^= (row & 7) << 4;  // inverse-swizzle the global source
            const char* src = bas + (size_t)row * ld + kb + (k0 << 1);
            gload16(src, ldsc + ellb);
        }
        __syncthreads();
#pragma unroll
        for (int ks = 0; ks < 2; ++ks) {
            half8 af[MT], bf[NT];
#pragma unroll
            for (int mt = 0; mt < MT; ++mt) {
                int row = wr * (MT * 16) + mt * 16 + (lane & 15);
                int byt = (row << 7) + (ks << 6) + ((lane >> 4) << 4);
                byt ^= (row & 7) << 4;
                af[mt] = *(const half8*)(ldsc + byt);
            }
#pragma unroll
            for (int nt = 0; nt < NT; ++nt) {
                int row = wc * (NT * 16) + nt * 16 + (lane & 15);
                int byt = (row << 7) + (ks << 6) + ((lane >> 4) << 4);
                byt ^= (row & 7) << 4;
                bf[nt] = *(const half8*)(ldsc + BM * 128 + byt);
            }
#pragma unroll
            for (int mt = 0; mt < MT; ++mt)
#pragma unroll
                for (int nt = 0; nt < NT; ++nt)
                    acc[mt][nt] = __builtin_amdgcn_mfma_f32_16x16x32_f16(af[mt], bf[nt], acc[mt][nt], 0, 0, 0);
        }
        __syncthreads();
    }
}

// ---------------- GEMM 1: silu(LN(x)@uv_w^T + b) -> u | vT | braw ----------
__global__ __launch_bounds__(256) void k_mm_uv(const f16* __restrict__ xn,
                                               const f16* __restrict__ wuv,
                                               const float* __restrict__ bias,
                                               f16* __restrict__ u,
                                               f16* __restrict__ vT,
                                               float* __restrict__ braw) {
    __shared__ union {
        f16 stage[256 * 64];
        f16 tr[128][136];
    } sl;
    const int m0 = blockIdx.y * 128, n0 = blockIdx.x * 128;
    f32x4 acc[4][4];
#pragma unroll
    for (int i = 0; i < 4; ++i)
#pragma unroll
        for (int j = 0; j < 4; ++j) acc[i][j] = (f32x4){0.f, 0.f, 0.f, 0.f};
    mfma_core<4, 4>((const char*)(xn + (size_t)m0 * H_DIM), H_DIM * 2,
                    (const char*)(wuv + (size_t)n0 * H_DIM), H_DIM * 2,
                    H_DIM, sl.stage, acc);
    const int lane = threadIdx.x & 63, wv = threadIdx.x >> 6;
    const int wr = wv >> 1, wc = wv & 1;
    if (n0 < E_DIM) {  // u region
#pragma unroll
        for (int mt = 0; mt < 4; ++mt)
#pragma unroll
            for (int nt = 0; nt < 4; ++nt)
#pragma unroll
                for (int r = 0; r < 4; ++r) {
                    int ml = wr * 64 + mt * 16 + (lane >> 4) * 4 + r;
                    int nl = wc * 64 + nt * 16 + (lane & 15);
                    float s = acc[mt][nt][r] + bias[n0 + nl];
                    float val = s / (1.f + expf(-s));
                    u[(size_t)(m0 + ml) * E_DIM + (n0 + nl)] = (f16)val;
                }
    } else if (n0 < 2 * E_DIM) {  // v region -> transposed store via LDS
#pragma unroll
        for (int mt = 0; mt < 4; ++mt)
#pragma unroll
            for (int nt = 0; nt < 4; ++nt)
#pragma unroll
                for (int r = 0; r < 4; ++r) {
                    int ml = wr * 64 + mt * 16 + (lane >> 4) * 4 + r;
                    int nl = wc * 64 + nt * 16 + (lane & 15);
                    float s = acc[mt][nt][r] + bias[n0 + nl];
                    sl.tr[nl][ml] = (f16)(s / (1.f + expf(-s)));
                }
        __syncthreads();
        int rl = threadIdx.x >> 1, h = threadIdx.x & 1;
        int b = m0 >> 12;
        int mloc = m0 & (L_DIM - 1);
        size_t e = (size_t)(n0 - E_DIM) + rl;
        f16* dst = vT + ((size_t)b * E_DIM + e) * L_DIM + mloc + h * 64;
#pragma unroll
        for (int i = 0; i < 8; ++i)
            *(uint4*)(dst + i * 8) = *(const uint4*)&sl.tr[rl][h * 64 + i * 8];
    } else {  // braw region (tile 16, width 128 == S_DIM)
#pragma unroll
        for (int mt = 0; mt < 4; ++mt)
#pragma unroll
            for (int nt = 0; nt < 4; ++nt)
#pragma unroll
                for (int r = 0; r < 4; ++r) {
                    int ml = wr * 64 + mt * 16 + (lane >> 4) * 4 + r;
                    int nl = wc * 64 + nt * 16 + (lane & 15);
                    float s = acc[mt][nt][r] + bias[n0 + nl];
                    braw[(size_t)(m0 + ml) * S_DIM + (n0 - 2 * E_DIM + nl)] =
                        s / (1.f + expf(-s));
                }
    }
}

// ---------------- gamma/beta + RoPE -> q, k (f16) ----------------
__global__ __launch_bounds__(256) void k_prep(const float* __restrict__ braw,
                                              const float* __restrict__ gamma,
                                              const float* __restrict__ beta,
                                              const float* __restrict__ cosT,
                                              const float* __restrict__ sinT,
                                              f16* __restrict__ q,
                                              f16* __restrict__ kq) {
    int idx = blockIdx.x * 256 + threadIdx.x;  // N_ROWS * 64
    int row = idx >> 6;
    int j = idx & 63;
    int l = row & (L_DIM - 1);
    float b1 = braw[(size_t)row * S_DIM + j];
    float b2 = braw[(size_t)row * S_DIM + j + HALF];
    float c = cosT[l * HALF + j];
    float s = sinT[l * HALF + j];
    {
        float x1 = b1 * gamma[j] + beta[j];
        float x2 = b2 * gamma[j + HALF] + beta[j + HALF];
        q[(size_t)row * S_DIM + j] = (f16)(x1 * c - x2 * s);
        q[(size_t)row * S_DIM + j + HALF] = (f16)(x2 * c + x1 * s);
    }
    {
        float x1 = b1 * gamma[S_DIM + j] + beta[S_DIM + j];
        float x2 = b2 * gamma[S_DIM + j + HALF] + beta[S_DIM + j + HALF];
        kq[(size_t)row * S_DIM + j] = (f16)(x1 * c - x2 * s);
        kq[(size_t)row * S_DIM + j + HALF] = (f16)(x2 * c + x1 * s);
    }
}

// ---------------- GEMM 2: kern_c = relu(q_chunk @ k^T /sqrt(S))^2 ----------
__global__ __launch_bounds__(256) void k_mm_qk(const f16* __restrict__ q,
                                               const f16* __restrict__ k,
                                               f16* __restrict__ kern, int mc) {
    __shared__ f16 stage[256 * 64];
    const int b = blockIdx.z;
    const int m0 = blockIdx.y * 128, n0 = blockIdx.x * 128;
    f32x4 acc[4][4];
#pragma unroll
    for (int i = 0; i < 4; ++i)
#pragma unroll
        for (int j = 0; j < 4; ++j) acc[i][j] = (f32x4){0.f, 0.f, 0.f, 0.f};
    const char* Ab = (const char*)(q + (size_t)(b * L_DIM + mc * 1024 + m0) * S_DIM);
    const char* Bb = (const char*)(k + (size_t)(b * L_DIM + n0) * S_DIM);
    mfma_core<4, 4>(Ab, S_DIM * 2, Bb, S_DIM * 2, S_DIM, stage, acc);
    const int lane = threadIdx.x & 63, wv = threadIdx.x >> 6;
    const int wr = wv >> 1, wc = wv & 1;
#pragma unroll
    for (int mt = 0; mt < 4; ++mt)
#pragma unroll
        for (int nt = 0; nt < 4; ++nt)
#pragma unroll
            for (int r = 0; r < 4; ++r) {
                int ml = wr * 64 + mt * 16 + (lane >> 4) * 4 + r;
                int nl = wc * 64 + nt * 16 + (lane & 15);
                float t = fmaxf(acc[mt][nt][r] * INV_SQRT_S, 0.f);
                t = fminf(t, 240.f);  // fp16-range guard (inert on real data)
                kern[(size_t)(b * 1024 + m0 + ml) * L_DIM + (n0 + nl)] = (f16)(t * t);
            }
}

// ---------------- GEMM 3: aub = u ⊙ (kern_c @ v) (chunk rows) --------------
__global__ __launch_bounds__(256) void k_mm_av(const f16* __restrict__ kern,
                                               const f16* __restrict__ vT,
                                               const f16* __restrict__ u,
                                               f16* __restrict__ aub, int mc) {
    __shared__ f16 stage[192 * 64];
    const int b = blockIdx.z;
    const int m0 = blockIdx.y * 128, n0 = blockIdx.x * 64;
    f32x4 acc[4][2];
#pragma unroll
    for (int i = 0; i < 4; ++i)
#pragma unroll
        for (int j = 0; j < 2; ++j) acc[i][j] = (f32x4){0.f, 0.f, 0.f, 0.f};
    const char* Ab = (const char*)(kern + (size_t)b * 1024 * L_DIM + (size_t)m0 * L_DIM);
    const char* Bb = (const char*)(vT + (size_t)b * E_DIM * L_DIM + (size_t)n0 * L_DIM);
    mfma_core<4, 2>(Ab, L_DIM * 2, Bb, L_DIM * 2, L_DIM, stage, acc);
    const int lane = threadIdx.x & 63, wv = threadIdx.x >> 6;
    const int wr = wv >> 1, wc = wv & 1;
#pragma unroll
    for (int mt = 0; mt < 4; ++mt)
#pragma unroll
        for (int nt = 0; nt < 2; ++nt)
#pragma unroll
            for (int r = 0; r < 4; ++r) {
                int ml = wr * 64 + mt * 16 + (lane >> 4) * 4 + r;
                int nl = wc * 32 + nt * 16 + (lane & 15);
                size_t mg = (size_t)b * L_DIM + mc * 1024 + m0 + ml;
                size_t n = n0 + nl;
                float val = acc[mt][nt][r] * (float)u[mg * E_DIM + n];
                val = fminf(fmaxf(val, -60000.f), 60000.f);  // fp16-range guard
                aub[mg * E_DIM + n] = (f16)val;
            }
}

// ---------------- GEMM 4: out = aub @ o_w^T + o_b + x ----------------------
__global__ __launch_bounds__(256) void k_mm_out(const f16* __restrict__ aub,
                                                const f16* __restrict__ wo,
                                                const float* __restrict__ ob,
                                                const float* __restrict__ x,
                                                float* __restrict__ out) {
    __shared__ f16 stage[256 * 64];
    const int m0 = blockIdx.y * 128, n0 = blockIdx.x * 128;
    f32x4 acc[4][4];
#pragma unroll
    for (int i = 0; i < 4; ++i)
#pragma unroll
        for (int j = 0; j < 4; ++j) acc[i][j] = (f32x4){0.f, 0.f, 0.f, 0.f};
    mfma_core<4, 4>((const char*)(aub + (size_t)m0 * E_DIM), E_DIM * 2,
                    (const char*)(wo + (size_t)n0 * E_DIM), E_DIM * 2,
                    E_DIM, stage, acc);
    const int lane = threadIdx.x & 63, wv = threadIdx.x >> 6;
    const int wr = wv >> 1, wc = wv & 1;
#pragma unroll
    for (int mt = 0; mt < 4; ++mt)
#pragma unroll
        for (int nt = 0; nt < 4; ++nt)
#pragma unroll
            for (int r = 0; r < 4; ++r) {
                int ml = wr * 64 + mt * 16 + (lane >> 4) * 4 + r;
                int nl = wc * 64 + nt * 16 + (lane & 15);
                size_t m = m0 + ml;
                size_t n = n0 + nl;
                out[m * H_DIM + n] = acc[mt][nt][r] + ob[n] + x[m * H_DIM + n];
            }
}

extern "C" void kernel_launch(void* const* d_in, const int* in_sizes, int n_in,
                              void* d_out, int out_size, void* d_ws, size_t ws_size,
                              hipStream_t stream) {
    const float* x     = (const float*)d_in[0];
    const float* ln_w  = (const float*)d_in[1];
    const float* ln_b  = (const float*)d_in[2];
    const float* uv_w  = (const float*)d_in[3];
    const float* uv_b  = (const float*)d_in[4];
    const float* gamma = (const float*)d_in[5];
    const float* beta  = (const float*)d_in[6];
    const float* o_w   = (const float*)d_in[7];
    const float* o_b   = (const float*)d_in[8];
    float* out = (float*)d_out;
    char* ws = (char*)d_ws;

    float* cosT = (float*)(ws + OFF_COS);
    float* sinT = (float*)(ws + OFF_SIN);
    float* muA  = (float*)(ws + OFF_MU);
    float* rsA  = (float*)(ws + OFF_RS);
    f16* xn   = (f16*)(ws + OFF_XN);
    f16* wuv  = (f16*)(ws + OFF_WUV);
    f16* wo   = (f16*)(ws + OFF_WO);
    f16* u    = (f16*)(ws + OFF_U);
    f16* vT   = (f16*)(ws + OFF_VT);
    float* braw = (float*)(ws + OFF_BR);
    f16* q    = (f16*)(ws + OFF_Q);
    f16* k    = (f16*)(ws + OFF_K);
    f16* kern = (f16*)(ws + OFF_KC);
    f16* aub  = (f16*)(ws + OFF_AUB);

    k_tables<<<1024, 256, 0, stream>>>(cosT, sinT);
    k_stats<<<N_ROWS, 256, 0, stream>>>(x, muA, rsA);
    k_cvt_w<<<1600, 256, 0, stream>>>(uv_w, o_w, wuv, wo);
    k_xn<<<8192, 256, 0, stream>>>(x, muA, rsA, ln_w, ln_b, xn);
    k_mm_uv<<<dim3(17, 128), 256, 0, stream>>>(xn, wuv, uv_b, u, vT, braw);
    k_prep<<<4096, 256, 0, stream>>>(braw, gamma, beta, cosT, sinT, q, k);
    for (int mc = 0; mc < 4; ++mc) {
        k_mm_qk<<<dim3(32, 8, 4), 256, 0, stream>>>(q, k, kern, mc);
        k_mm_av<<<dim3(16, 8, 4), 256, 0, stream>>>(kern, vT, u, aub, mc);
    }
    k_mm_out<<<dim3(4, 128), 256, 0, stream>>>(aub, wo, o_b, x, out);
}